// Round 3
// baseline (488.857 us; speedup 1.0000x reference)
//
#include <hip/hip_runtime.h>
#include <stdint.h>

#define T_DIM   8192
#define IN_DIM  4096
#define OUT_DIM 4096
#define RANK    8

typedef int   v4i  __attribute__((ext_vector_type(4)));
typedef int   v16i __attribute__((ext_vector_type(16)));
typedef short v8s  __attribute__((ext_vector_type(8)));
typedef float v4f  __attribute__((ext_vector_type(4)));

__device__ __forceinline__ void async_copy16(const void* g, void* l) {
  __builtin_amdgcn_global_load_lds(
      (const __attribute__((address_space(1))) void*)g,
      (__attribute__((address_space(3))) void*)l, 16, 0, 0);
}

// round-to-nearest-even fp32 -> bf16 bits
__device__ __forceinline__ unsigned short f2bf_rne(float f) {
  unsigned int x = __builtin_bit_cast(unsigned int, f);
  return (unsigned short)((x + 0x7fffu + ((x >> 16) & 1u)) >> 16);
}

// ---------------------------------------------------------------------------
// Kernel 0: pack weight int32->int8, and lora_a fp32->bf16 (padded to 16 rows)
// ---------------------------------------------------------------------------
#define PACKW_BLOCKS 16384  // 4096*4096/4/256
#define PACKA_BLOCKS 256    // 16*4096/256

__global__ __launch_bounds__(256) void pack_inputs(
    const int* __restrict__ w32, const float* __restrict__ lora_a,
    int8_t* __restrict__ w8, unsigned short* __restrict__ a_bf)
{
  const int b = blockIdx.x;
  if (b < PACKW_BLOCKS) {
    const int idx = b * 256 + threadIdx.x;
    const int4 v = ((const int4*)w32)[idx];
    char4 q;
    q.x = (signed char)v.x; q.y = (signed char)v.y;
    q.z = (signed char)v.z; q.w = (signed char)v.w;
    ((char4*)w8)[idx] = q;
  } else {
    const int idx = (b - PACKW_BLOCKS) * 256 + threadIdx.x;  // 0..65535
    const int r = idx >> 12;           // 0..15
    const int k = idx & (IN_DIM - 1);
    const float v = (r < RANK) ? lora_a[(size_t)r * IN_DIM + k] : 0.f;
    a_bf[idx] = f2bf_rne(v);
  }
}

// ---------------------------------------------------------------------------
// Kernel 1: per-row amax + int8 quantization. One block per row, no lora work.
// ---------------------------------------------------------------------------
__global__ __launch_bounds__(256) void quant_row(
    const float* __restrict__ x, int8_t* __restrict__ x_i8,
    float* __restrict__ x_scale)
{
  const int row = blockIdx.x;
  const int tid = threadIdx.x;
  const float4* xr = (const float4*)(x + (size_t)row * IN_DIM);
  float4 xv[4];
#pragma unroll
  for (int c = 0; c < 4; ++c) xv[c] = xr[c * 256 + tid];

  float am = 0.f;
#pragma unroll
  for (int c = 0; c < 4; ++c)
    am = fmaxf(am, fmaxf(fmaxf(fabsf(xv[c].x), fabsf(xv[c].y)),
                         fmaxf(fabsf(xv[c].z), fabsf(xv[c].w))));
#pragma unroll
  for (int off = 32; off > 0; off >>= 1)
    am = fmaxf(am, __shfl_xor(am, off, 64));

  __shared__ float red[4];
  if ((tid & 63) == 0) red[tid >> 6] = am;
  __syncthreads();
  const float amax = fmaxf(fmaxf(red[0], red[1]), fmaxf(red[2], red[3]));
  const float scale = amax * (1.0f / 127.0f);
  const float inv = 1.0f / fmaxf(scale, 1e-12f);

  char4* qout = (char4*)(x_i8 + (size_t)row * IN_DIM);
#pragma unroll
  for (int c = 0; c < 4; ++c) {
    char4 q;
    q.x = (signed char)(int)rintf(xv[c].x * inv);
    q.y = (signed char)(int)rintf(xv[c].y * inv);
    q.z = (signed char)(int)rintf(xv[c].z * inv);
    q.w = (signed char)(int)rintf(xv[c].w * inv);
    qout[c * 256 + tid] = q;
  }
  if (tid == 0) x_scale[row] = scale;
}

// ---------------------------------------------------------------------------
// Kernel 2: xa = (x_i8 * scale) @ lora_a^T via bf16 MFMA (int8 exact in bf16).
// 128 blocks x 256 thr; wave handles 16 rows; K-loop over 4096 in steps of 32.
// ---------------------------------------------------------------------------
__global__ __launch_bounds__(256) void xa_mfma(
    const int8_t* __restrict__ x_i8, const float* __restrict__ x_scale,
    const unsigned short* __restrict__ a_bf,  // [16][IN] bf16, rows 8..15 zero
    float* __restrict__ xa)                   // [T][RANK]
{
  const int tid = threadIdx.x;
  const int lane = tid & 63, wave = tid >> 6;
  const int row0 = blockIdx.x * 64 + wave * 16;
  const int m16 = lane & 15, quad = lane >> 4;

  v4f acc = {0.f, 0.f, 0.f, 0.f};
  const int8_t* arow = x_i8 + (size_t)(row0 + m16) * IN_DIM + quad * 8;
  const unsigned short* brow = a_bf + (size_t)m16 * IN_DIM + quad * 8;

  for (int k0 = 0; k0 < IN_DIM; k0 += 32) {
    const uint2 a8 = *(const uint2*)(arow + k0);
    v8s aF;
#pragma unroll
    for (int j = 0; j < 8; ++j) {
      const unsigned int word = (j < 4) ? a8.x : a8.y;
      const signed char sc = (signed char)((word >> ((j & 3) * 8)) & 0xff);
      // integers |v|<=127 are exact in bf16: truncation suffices
      aF[j] = (short)(__builtin_bit_cast(unsigned int, (float)(int)sc) >> 16);
    }
    const v8s bF = *(const v8s*)(brow + k0);
    acc = __builtin_amdgcn_mfma_f32_16x16x32_bf16(aF, bF, acc, 0, 0, 0);
  }
  // C/D: col = lane&15 (rank), row = quad*4 + reg
  const int r = row0 + quad * 4;
  if (m16 < RANK) {
#pragma unroll
    for (int reg = 0; reg < 4; ++reg)
      xa[(size_t)(r + reg) * RANK + m16] = acc[reg] * x_scale[r + reg];
  }
}

// ---------------------------------------------------------------------------
// Kernel 3: C = dequant(x_i8 @ W^T) + xa @ lora_b^T
// BM=BN=128, BK=64, 256 thr (4 waves 2x2, 64x64/wave), mfma_i32_32x32x32_i8.
// ---------------------------------------------------------------------------
__global__ __launch_bounds__(256) void int8_gemm_lora(
    const int8_t* __restrict__ A,       // x_i8 [T, IN]
    const int8_t* __restrict__ B,       // w8 [OUT, IN]
    const float* __restrict__ x_scale,  // [T]
    const float* __restrict__ w_scale,  // [OUT]
    const float* __restrict__ xa,       // [T, RANK]
    const float* __restrict__ lora_b,   // [OUT, RANK]
    float* __restrict__ out)            // [T, OUT]
{
  __shared__ __align__(16) int8_t As[128 * 64];
  __shared__ __align__(16) int8_t Bs[128 * 64];
  __shared__ float xs_s[128];
  __shared__ float ws_s[128];
  __shared__ __align__(16) float xa_s[128 * RANK];
  __shared__ __align__(16) float lb_s[128 * RANK];

  const int tid = threadIdx.x;
  const int bx = blockIdx.x & 31;
  const int by = blockIdx.x >> 5;
  const size_t arow0 = (size_t)by * 128;
  const size_t brow0 = (size_t)bx * 128;

  if (tid < 128) xs_s[tid] = x_scale[arow0 + tid];
  else           ws_s[tid - 128] = w_scale[brow0 + (tid - 128)];
  ((float4*)xa_s)[tid] = ((const float4*)(xa + arow0 * RANK))[tid];
  ((float4*)lb_s)[tid] = ((const float4*)(lora_b + brow0 * RANK))[tid];

  v16i acc[2][2];
#pragma unroll
  for (int i = 0; i < 2; ++i)
#pragma unroll
    for (int j = 0; j < 2; ++j)
#pragma unroll
      for (int e = 0; e < 16; ++e) acc[i][j][e] = 0;

  const int lane = tid & 63;
  const int wave = tid >> 6;
  const int wr = wave >> 1, wc = wave & 1;
  const int l31 = lane & 31, lh = lane >> 5;

  // frag: row = l31 (within 32-tile), k = ks*32 + lh*16 + [0,16)
  const int8_t* a_frag_base = As + (wr * 64 + l31) * 64 + lh * 16;
  const int8_t* b_frag_base = Bs + (wc * 64 + l31) * 64 + lh * 16;

  const int off0 = tid * 16;
  const int r0 = tid >> 2;
  const int c0 = (tid & 3) * 16;
  const int8_t* a_src = A + (arow0 + (size_t)r0) * IN_DIM + c0;
  const int8_t* b_src = B + (brow0 + (size_t)r0) * IN_DIM + c0;

  for (int k0 = 0; k0 < IN_DIM; k0 += 64) {
    async_copy16(a_src + k0,                       As + off0);
    async_copy16(a_src + (size_t)64 * IN_DIM + k0, As + 4096 + off0);
    async_copy16(b_src + k0,                       Bs + off0);
    async_copy16(b_src + (size_t)64 * IN_DIM + k0, Bs + 4096 + off0);
    __syncthreads();

    v4i aF[2][2], bF[2][2];  // [ks][tile]
#pragma unroll
    for (int ks = 0; ks < 2; ++ks) {
#pragma unroll
      for (int i = 0; i < 2; ++i) {
        aF[ks][i] = *(const v4i*)(a_frag_base + i * 32 * 64 + ks * 32);
        bF[ks][i] = *(const v4i*)(b_frag_base + i * 32 * 64 + ks * 32);
      }
    }
#pragma unroll
    for (int ks = 0; ks < 2; ++ks)
#pragma unroll
      for (int i = 0; i < 2; ++i)
#pragma unroll
        for (int j = 0; j < 2; ++j)
          acc[i][j] = __builtin_amdgcn_mfma_i32_32x32x32_i8(
              aF[ks][i], bF[ks][j], acc[i][j], 0, 0, 0);
    __syncthreads();
  }

  // Epilogue. 32x32 C/D: col = lane&31, row = (reg&3) + 8*(reg>>2) + 4*lh
  float wscv[2];
  float4 lb0v[2], lb1v[2];
  int colv[2];
#pragma unroll
  for (int j = 0; j < 2; ++j) {
    const int c = wc * 64 + j * 32 + l31;
    colv[j] = c;
    wscv[j] = ws_s[c];
    lb0v[j] = *(const float4*)(lb_s + c * RANK);
    lb1v[j] = *(const float4*)(lb_s + c * RANK + 4);
  }
#pragma unroll
  for (int i = 0; i < 2; ++i) {
#pragma unroll
    for (int reg = 0; reg < 16; ++reg) {
      const int rit = (reg & 3) + 8 * (reg >> 2) + 4 * lh;
      const int r = wr * 64 + i * 32 + rit;
      const float xsc = xs_s[r];
      const float4 xa0 = *(const float4*)(xa_s + r * RANK);
      const float4 xa1 = *(const float4*)(xa_s + r * RANK + 4);
      float* orow = out + (arow0 + (size_t)r) * OUT_DIM + brow0;
#pragma unroll
      for (int j = 0; j < 2; ++j) {
        float v = (float)acc[i][j][reg] * xsc * wscv[j];
        v += xa0.x * lb0v[j].x + xa0.y * lb0v[j].y + xa0.z * lb0v[j].z + xa0.w * lb0v[j].w +
             xa1.x * lb1v[j].x + xa1.y * lb1v[j].y + xa1.z * lb1v[j].z + xa1.w * lb1v[j].w;
        orow[colv[j]] = v;
      }
    }
  }
}

// ---------------------------------------------------------------------------
extern "C" void kernel_launch(void* const* d_in, const int* in_sizes, int n_in,
                              void* d_out, int out_size, void* d_ws, size_t ws_size,
                              hipStream_t stream) {
  const float* x       = (const float*)d_in[0];
  const int*   w_i32   = (const int*)d_in[1];    // integer inputs upload as int32
  const float* w_scale = (const float*)d_in[2];
  const float* lora_a  = (const float*)d_in[3];
  const float* lora_b  = (const float*)d_in[4];
  float* out = (float*)d_out;

  // ws: x_i8 | w8 | a_bf[16][IN] | x_scale | xa
  int8_t* x_i8 = (int8_t*)d_ws;
  int8_t* w8   = x_i8 + (size_t)T_DIM * IN_DIM;
  unsigned short* a_bf = (unsigned short*)(w8 + (size_t)OUT_DIM * IN_DIM);
  float* x_scale = (float*)(a_bf + 16 * IN_DIM);
  float* xa      = x_scale + T_DIM;

  pack_inputs<<<PACKW_BLOCKS + PACKA_BLOCKS, 256, 0, stream>>>(w_i32, lora_a, w8, a_bf);
  quant_row<<<T_DIM, 256, 0, stream>>>(x, x_i8, x_scale);
  xa_mfma<<<T_DIM / 64, 256, 0, stream>>>(x_i8, x_scale, a_bf, xa);
  int8_gemm_lora<<<(T_DIM / 128) * (OUT_DIM / 128), 256, 0, stream>>>(
      x_i8, w8, x_scale, w_scale, xa, lora_b, out);
}

// Round 4
// 453.561 us; speedup vs baseline: 1.0778x; 1.0778x over previous
//
#include <hip/hip_runtime.h>
#include <stdint.h>

#define T_DIM   8192
#define IN_DIM  4096
#define OUT_DIM 4096
#define RANK    8

typedef int v4i __attribute__((ext_vector_type(4)));

__device__ __forceinline__ void async_copy16(const void* g, void* l) {
  __builtin_amdgcn_global_load_lds(
      (const __attribute__((address_space(1))) void*)g,
      (__attribute__((address_space(3))) void*)l, 16, 0, 0);
}

// ---------------------------------------------------------------------------
// Kernel 0 "prep": one launch, block-uniform sections.
//  [0, 16384)              : pack weight int32 -> int8
//  [16384, 16384+8192)     : per-row x quant (amax + int8 write + x_scale)
//  [+0, +16)               : lora_a per-rank int8 quant (rows 8..15 zero pad)
//  [+16, +16+64)           : zero xa accumulator
// ---------------------------------------------------------------------------
#define PW_BLOCKS 16384
#define QX_BLOCKS 8192
#define LA_BLOCKS 16
#define XZ_BLOCKS 64
#define PREP_BLOCKS (PW_BLOCKS + QX_BLOCKS + LA_BLOCKS + XZ_BLOCKS)

__global__ __launch_bounds__(256) void prep(
    const int* __restrict__ w32,       // [OUT*IN] int32
    const float* __restrict__ x,       // [T, IN]
    const float* __restrict__ lora_a,  // [RANK, IN]
    int8_t* __restrict__ w8,           // [OUT*IN]
    int8_t* __restrict__ x_i8,         // [T, IN]
    float* __restrict__ x_scale,       // [T]
    int8_t* __restrict__ a_i8,         // [16, IN] (rows 8..15 zero)
    float* __restrict__ a_scale,       // [16]
    float* __restrict__ xa)            // [T, RANK] -> zeroed
{
  const int b = blockIdx.x;
  const int tid = threadIdx.x;
  __shared__ float red[4];

  if (b < PW_BLOCKS) {
    const int idx = b * 256 + tid;
    const int4 v = ((const int4*)w32)[idx];
    char4 q;
    q.x = (signed char)v.x; q.y = (signed char)v.y;
    q.z = (signed char)v.z; q.w = (signed char)v.w;
    ((char4*)w8)[idx] = q;
    return;
  }
  if (b < PW_BLOCKS + QX_BLOCKS) {
    const int row = b - PW_BLOCKS;
    const float4* xr = (const float4*)(x + (size_t)row * IN_DIM);
    float4 xv[4];
#pragma unroll
    for (int c = 0; c < 4; ++c) xv[c] = xr[c * 256 + tid];
    float am = 0.f;
#pragma unroll
    for (int c = 0; c < 4; ++c)
      am = fmaxf(am, fmaxf(fmaxf(fabsf(xv[c].x), fabsf(xv[c].y)),
                           fmaxf(fabsf(xv[c].z), fabsf(xv[c].w))));
#pragma unroll
    for (int off = 32; off > 0; off >>= 1)
      am = fmaxf(am, __shfl_xor(am, off, 64));
    if ((tid & 63) == 0) red[tid >> 6] = am;
    __syncthreads();
    const float amax = fmaxf(fmaxf(red[0], red[1]), fmaxf(red[2], red[3]));
    const float scale = amax * (1.0f / 127.0f);
    const float inv = 1.0f / fmaxf(scale, 1e-12f);
    char4* qout = (char4*)(x_i8 + (size_t)row * IN_DIM);
#pragma unroll
    for (int c = 0; c < 4; ++c) {
      char4 q;
      q.x = (signed char)(int)rintf(xv[c].x * inv);
      q.y = (signed char)(int)rintf(xv[c].y * inv);
      q.z = (signed char)(int)rintf(xv[c].z * inv);
      q.w = (signed char)(int)rintf(xv[c].w * inv);
      qout[c * 256 + tid] = q;
    }
    if (tid == 0) x_scale[row] = scale;
    return;
  }
  if (b < PW_BLOCKS + QX_BLOCKS + LA_BLOCKS) {
    const int r = b - (PW_BLOCKS + QX_BLOCKS);  // 0..15
    if (r >= RANK) {  // zero pad rows 8..15
      ((int4*)(a_i8 + (size_t)r * IN_DIM))[tid] = int4{0, 0, 0, 0};
      if (tid == 0) a_scale[r] = 0.f;
      return;
    }
    const float4* ar = (const float4*)(lora_a + (size_t)r * IN_DIM);
    float4 av[4];
#pragma unroll
    for (int c = 0; c < 4; ++c) av[c] = ar[c * 256 + tid];
    float am = 0.f;
#pragma unroll
    for (int c = 0; c < 4; ++c)
      am = fmaxf(am, fmaxf(fmaxf(fabsf(av[c].x), fabsf(av[c].y)),
                           fmaxf(fabsf(av[c].z), fabsf(av[c].w))));
#pragma unroll
    for (int off = 32; off > 0; off >>= 1)
      am = fmaxf(am, __shfl_xor(am, off, 64));
    if ((tid & 63) == 0) red[tid >> 6] = am;
    __syncthreads();
    const float amax = fmaxf(fmaxf(red[0], red[1]), fmaxf(red[2], red[3]));
    const float scale = amax * (1.0f / 127.0f);
    const float inv = 1.0f / fmaxf(scale, 1e-12f);
    char4* qout = (char4*)(a_i8 + (size_t)r * IN_DIM);
#pragma unroll
    for (int c = 0; c < 4; ++c) {
      char4 q;
      q.x = (signed char)(int)rintf(av[c].x * inv);
      q.y = (signed char)(int)rintf(av[c].y * inv);
      q.z = (signed char)(int)rintf(av[c].z * inv);
      q.w = (signed char)(int)rintf(av[c].w * inv);
      qout[c * 256 + tid] = q;
    }
    if (tid == 0) a_scale[r] = scale;
    return;
  }
  // zero xa: 64 blocks x 256 threads x 16 B = 256 KB
  const int idx = (b - (PW_BLOCKS + QX_BLOCKS + LA_BLOCKS)) * 256 + tid;
  ((float4*)xa)[idx] = float4{0.f, 0.f, 0.f, 0.f};
}

// ---------------------------------------------------------------------------
// Kernel 1: xa += (x_i8 @ a_i8^T) * xs * as  via mfma_i32_16x16x64_i8.
// K-split x8, 1024 blocks x 4 waves; wave covers 16 rows x K-chunk 512.
// fp32 atomicAdd into xa (partials < 2^24: exact).
// ---------------------------------------------------------------------------
__global__ __launch_bounds__(256) void xa_i8(
    const int8_t* __restrict__ x_i8, const float* __restrict__ x_scale,
    const int8_t* __restrict__ a_i8, const float* __restrict__ a_scale,
    float* __restrict__ xa)
{
  const int tid = threadIdx.x;
  const int lane = tid & 63, wave = tid >> 6;
  const int kb = blockIdx.x & 7;      // K-split index
  const int rb = blockIdx.x >> 3;     // row-block 0..127
  const int m16 = lane & 15, quad = lane >> 4;
  const int row0 = rb * 64 + wave * 16;
  const int kbase = kb * 512;

  v4i acc = {0, 0, 0, 0};
  const int8_t* ap = x_i8 + (size_t)(row0 + m16) * IN_DIM + kbase + quad * 16;
  const int8_t* bp = a_i8 + (size_t)m16 * IN_DIM + kbase + quad * 16;
#pragma unroll
  for (int k = 0; k < 512; k += 64)
    acc = __builtin_amdgcn_mfma_i32_16x16x64_i8(
        *(const v4i*)(ap + k), *(const v4i*)(bp + k), acc, 0, 0, 0);

  // C/D: col = lane&15 (rank), row = quad*4 + reg
  if (m16 < RANK) {
    const float asc = a_scale[m16];
    const int r = row0 + quad * 4;
#pragma unroll
    for (int reg = 0; reg < 4; ++reg)
      atomicAdd(&xa[(size_t)(r + reg) * RANK + m16],
                (float)acc[reg] * x_scale[r + reg] * asc);
  }
}

// ---------------------------------------------------------------------------
// Kernel 2: C = dequant(x_i8 @ W^T) + xa @ lora_b^T   (R2 structure, 16x16x64)
// ---------------------------------------------------------------------------
__global__ __launch_bounds__(256) void int8_gemm_lora(
    const int8_t* __restrict__ A,       // x_i8 [T, IN]
    const int8_t* __restrict__ B,       // w8 [OUT, IN]
    const float* __restrict__ x_scale,  // [T]
    const float* __restrict__ w_scale,  // [OUT]
    const float* __restrict__ xa,       // [T, RANK]
    const float* __restrict__ lora_b,   // [OUT, RANK]
    float* __restrict__ out)            // [T, OUT]
{
  __shared__ __align__(16) int8_t As[128 * 64];
  __shared__ __align__(16) int8_t Bs[128 * 64];
  __shared__ float xs_s[128];
  __shared__ float ws_s[128];
  __shared__ __align__(16) float xa_s[128 * RANK];
  __shared__ __align__(16) float lb_s[128 * RANK];

  const int tid = threadIdx.x;
  const int bx = blockIdx.x & 31;
  const int by = blockIdx.x >> 5;
  const size_t arow0 = (size_t)by * 128;
  const size_t brow0 = (size_t)bx * 128;

  if (tid < 128) xs_s[tid] = x_scale[arow0 + tid];
  else           ws_s[tid - 128] = w_scale[brow0 + (tid - 128)];
  ((float4*)xa_s)[tid] = ((const float4*)(xa + arow0 * RANK))[tid];
  ((float4*)lb_s)[tid] = ((const float4*)(lora_b + brow0 * RANK))[tid];

  v4i acc[4][4];
  const v4i vzero = {0, 0, 0, 0};
#pragma unroll
  for (int i = 0; i < 4; ++i)
#pragma unroll
    for (int j = 0; j < 4; ++j) acc[i][j] = vzero;

  const int lane = tid & 63;
  const int wave = tid >> 6;
  const int wr = wave >> 1, wc = wave & 1;
  const int quad = lane >> 4, m16 = lane & 15;

  const int8_t* a_frag_base = As + ((wr * 64 + m16) * 64 + quad * 16);
  const int8_t* b_frag_base = Bs + ((wc * 64 + m16) * 64 + quad * 16);

  const int off0 = tid * 16;
  const int r0 = tid >> 2;
  const int c0 = (tid & 3) * 16;
  const int8_t* a_src = A + (arow0 + (size_t)r0) * IN_DIM + c0;
  const int8_t* b_src = B + (brow0 + (size_t)r0) * IN_DIM + c0;

  for (int k0 = 0; k0 < IN_DIM; k0 += 64) {
    async_copy16(a_src + k0,                       As + off0);
    async_copy16(a_src + (size_t)64 * IN_DIM + k0, As + 4096 + off0);
    async_copy16(b_src + k0,                       Bs + off0);
    async_copy16(b_src + (size_t)64 * IN_DIM + k0, Bs + 4096 + off0);
    __syncthreads();

    v4i aF[4], bF[4];
#pragma unroll
    for (int i = 0; i < 4; ++i) aF[i] = *(const v4i*)(a_frag_base + i * 16 * 64);
#pragma unroll
    for (int j = 0; j < 4; ++j) bF[j] = *(const v4i*)(b_frag_base + j * 16 * 64);
#pragma unroll
    for (int i = 0; i < 4; ++i)
#pragma unroll
      for (int j = 0; j < 4; ++j)
        acc[i][j] = __builtin_amdgcn_mfma_i32_16x16x64_i8(aF[i], bF[j], acc[i][j], 0, 0, 0);
    __syncthreads();
  }

  float wscv[4];
  float4 lb0[4], lb1[4];
  int cols[4];
#pragma unroll
  for (int j = 0; j < 4; ++j) {
    const int c = wc * 64 + j * 16 + m16;
    cols[j] = c;
    wscv[j] = ws_s[c];
    lb0[j] = *(const float4*)(lb_s + c * RANK);
    lb1[j] = *(const float4*)(lb_s + c * RANK + 4);
  }
#pragma unroll
  for (int i = 0; i < 4; ++i) {
#pragma unroll
    for (int reg = 0; reg < 4; ++reg) {
      const int r = wr * 64 + i * 16 + quad * 4 + reg;
      const float xsc = xs_s[r];
      const float4 xa0 = *(const float4*)(xa_s + r * RANK);
      const float4 xa1 = *(const float4*)(xa_s + r * RANK + 4);
      float* orow = out + (arow0 + (size_t)r) * OUT_DIM + brow0;
#pragma unroll
      for (int j = 0; j < 4; ++j) {
        float v = (float)acc[i][j][reg] * xsc * wscv[j];
        v += xa0.x * lb0[j].x + xa0.y * lb0[j].y + xa0.z * lb0[j].z + xa0.w * lb0[j].w +
             xa1.x * lb1[j].x + xa1.y * lb1[j].y + xa1.z * lb1[j].z + xa1.w * lb1[j].w;
        orow[cols[j]] = v;
      }
    }
  }
}

// ---------------------------------------------------------------------------
extern "C" void kernel_launch(void* const* d_in, const int* in_sizes, int n_in,
                              void* d_out, int out_size, void* d_ws, size_t ws_size,
                              hipStream_t stream) {
  const float* x       = (const float*)d_in[0];
  const int*   w_i32   = (const int*)d_in[1];    // integer inputs upload as int32
  const float* w_scale = (const float*)d_in[2];
  const float* lora_a  = (const float*)d_in[3];
  const float* lora_b  = (const float*)d_in[4];
  float* out = (float*)d_out;

  // ws: x_i8 | w8 | a_i8[16][IN] | a_scale[16] | x_scale[T] | xa[T][RANK]
  int8_t* x_i8   = (int8_t*)d_ws;
  int8_t* w8     = x_i8 + (size_t)T_DIM * IN_DIM;
  int8_t* a_i8   = w8 + (size_t)OUT_DIM * IN_DIM;
  float*  a_scale = (float*)(a_i8 + (size_t)16 * IN_DIM);
  float*  x_scale = a_scale + 16;
  float*  xa      = x_scale + T_DIM;

  prep<<<PREP_BLOCKS, 256, 0, stream>>>(w_i32, x, lora_a, w8, x_i8, x_scale,
                                        a_i8, a_scale, xa);
  xa_i8<<<(T_DIM / 64) * 8, 256, 0, stream>>>(x_i8, x_scale, a_i8, a_scale, xa);
  int8_gemm_lora<<<(T_DIM / 128) * (OUT_DIM / 128), 256, 0, stream>>>(
      x_i8, w8, x_scale, w_scale, xa, lora_b, out);
}